// Round 1
// baseline (1211.119 us; speedup 1.0000x reference)
//
#include <hip/hip_runtime.h>

// QLSTM: B=512, T=1024, IN=1, H=64.
// One wave (64 lanes) per batch element; lane l owns hidden unit l and gate
// rows {l, 64+l, 128+l, 192+l} (i,f,g,o). W_hh rows held in registers
// (256 fp32/lane; __launch_bounds__(64,1) lets the allocator use the full
// unified VGPR/AGPR file). h broadcast through LDS each step (same-address
// float4 reads are conflict-free broadcasts).

#define TLEN 1024
#define HID  64

__device__ __forceinline__ float fast_sigmoid(float x) {
    // 1/(1+exp(-x)) with hw exp + hw rcp (~1 ulp each)
    return __builtin_amdgcn_rcpf(1.0f + __expf(-x));
}
__device__ __forceinline__ float fast_tanh(float x) {
    // tanh(x) = 2*sigmoid(2x) - 1
    return __builtin_fmaf(2.0f, fast_sigmoid(2.0f * x), -1.0f);
}

__global__ __launch_bounds__(64, 1)
void qlstm_kernel(const float* __restrict__ x,      // [B, T, 1]
                  const float* __restrict__ W_ih,   // [256, 1]
                  const float* __restrict__ W_hh,   // [256, 64]
                  const float* __restrict__ b_ih,   // [256]
                  const float* __restrict__ b_hh,   // [256]
                  const float* __restrict__ W_lin,  // [1, 64]
                  const float* __restrict__ b_lin,  // [1]
                  float* __restrict__ out)          // [B]
{
    const int b = blockIdx.x;
    const int l = threadIdx.x;   // 0..63, hidden unit index

    __shared__ __align__(16) float xs[TLEN];
    __shared__ __align__(16) float hs[HID];

    // Stage this batch element's x row (coalesced).
    const float* xrow = x + (size_t)b * TLEN;
    #pragma unroll
    for (int t = 0; t < TLEN / 64; ++t)
        xs[t * 64 + l] = xrow[t * 64 + l];

    // Load the 4 gate rows for hidden unit l into registers.
    float w[4][HID];
    #pragma unroll
    for (int g = 0; g < 4; ++g) {
        const float4* Wr = (const float4*)(W_hh + (size_t)(g * HID + l) * HID);
        #pragma unroll
        for (int k4 = 0; k4 < HID / 4; ++k4) {
            float4 a = Wr[k4];
            w[g][4 * k4 + 0] = a.x;
            w[g][4 * k4 + 1] = a.y;
            w[g][4 * k4 + 2] = a.z;
            w[g][4 * k4 + 3] = a.w;
        }
    }

    float u[4], bias[4];
    #pragma unroll
    for (int g = 0; g < 4; ++g) {
        u[g]    = W_ih[g * HID + l];                       // IN == 1
        bias[g] = b_ih[g * HID + l] + b_hh[g * HID + l];
    }
    const float wlin = W_lin[l];

    float h = 0.0f, c = 0.0f;
    hs[l] = 0.0f;
    __syncthreads();

    for (int t = 0; t < TLEN; ++t) {
        const float xt = xs[t];
        float acc[4];
        #pragma unroll
        for (int g = 0; g < 4; ++g)
            acc[g] = __builtin_fmaf(xt, u[g], bias[g]);

        // gates += h @ W_hh.T  (h broadcast from LDS, weights in registers)
        #pragma unroll
        for (int k4 = 0; k4 < HID / 4; ++k4) {
            const float4 hk = *(const float4*)&hs[4 * k4];
            #pragma unroll
            for (int g = 0; g < 4; ++g) {
                acc[g] = __builtin_fmaf(hk.x, w[g][4 * k4 + 0], acc[g]);
                acc[g] = __builtin_fmaf(hk.y, w[g][4 * k4 + 1], acc[g]);
                acc[g] = __builtin_fmaf(hk.z, w[g][4 * k4 + 2], acc[g]);
                acc[g] = __builtin_fmaf(hk.w, w[g][4 * k4 + 3], acc[g]);
            }
        }

        const float ig = fast_sigmoid(acc[0]);
        const float fg = fast_sigmoid(acc[1]);
        const float gg = fast_tanh(acc[2]);
        const float og = fast_sigmoid(acc[3]);
        c = __builtin_fmaf(fg, c, ig * gg);
        h = og * fast_tanh(c);

        __syncthreads();          // all lanes done reading old hs
        hs[l] = h;
        __syncthreads();          // new hs visible before next step's reads
    }

    // out[b] = dot(h, W_lin) + b_lin — wave-64 shuffle reduction.
    float v = h * wlin;
    #pragma unroll
    for (int off = 32; off > 0; off >>= 1)
        v += __shfl_down(v, off, 64);
    if (l == 0)
        out[b] = v + b_lin[0];
}

extern "C" void kernel_launch(void* const* d_in, const int* in_sizes, int n_in,
                              void* d_out, int out_size, void* d_ws, size_t ws_size,
                              hipStream_t stream) {
    const float* x     = (const float*)d_in[0];
    const float* W_ih  = (const float*)d_in[1];
    const float* W_hh  = (const float*)d_in[2];
    const float* b_ih  = (const float*)d_in[3];
    const float* b_hh  = (const float*)d_in[4];
    const float* W_lin = (const float*)d_in[5];
    const float* b_lin = (const float*)d_in[6];
    float* out = (float*)d_out;

    const int B = out_size;  // 512
    qlstm_kernel<<<B, 64, 0, stream>>>(x, W_ih, W_hh, b_ih, b_hh, W_lin, b_lin, out);
}

// Round 2
// 584.286 us; speedup vs baseline: 2.0728x; 2.0728x over previous
//
#include <hip/hip_runtime.h>

// QLSTM: B=512, T=1024, IN=1, H=64.
// 4 waves per batch element (block=256), one gate per wave:
//   wave 0 -> i, wave 1 -> f, wave 2 -> g, wave 3 -> o   (PyTorch order)
// Lane l owns hidden unit l. Each wave holds its 64-wide gate row in VGPRs
// (16 float4 = 64 VGPRs; total ~110 -> no AGPR/scratch traffic, 2 waves/SIMD).
//
// Sync structure (1 barrier/step):
//  - each wave keeps a PRIVATE LDS copy hs4[w][64] of the h vector; write then
//    read is same-wave DS ordering -> no barrier needed for the h broadcast.
//  - the c,h update is computed redundantly by all 4 waves; the only
//    cross-wave traffic is the 4 gate activations, exchanged through a
//    DOUBLE-BUFFERED act array (parity t&1) -> no WAR barrier.

#define TLEN 1024
#define HID  64

__device__ __forceinline__ float fast_sigmoid(float x) {
    return __builtin_amdgcn_rcpf(1.0f + __expf(-x));   // hw exp + hw rcp
}
__device__ __forceinline__ float fast_tanh(float x) {
    return __builtin_fmaf(2.0f, fast_sigmoid(2.0f * x), -1.0f);
}

__global__ __launch_bounds__(256, 2)
void qlstm_kernel(const float* __restrict__ x,      // [B, T, 1]
                  const float* __restrict__ W_ih,   // [256, 1]
                  const float* __restrict__ W_hh,   // [256, 64]
                  const float* __restrict__ b_ih,   // [256]
                  const float* __restrict__ b_hh,   // [256]
                  const float* __restrict__ W_lin,  // [1, 64]
                  const float* __restrict__ b_lin,  // [1]
                  float* __restrict__ out)          // [B]
{
    const int b   = blockIdx.x;
    const int tid = threadIdx.x;
    const int w   = tid >> 6;   // wave id == gate id
    const int l   = tid & 63;   // hidden unit

    __shared__ __align__(16) float xs[TLEN];          // 4 KB
    __shared__ __align__(16) float hs4[4][HID];       // per-wave private h
    __shared__ __align__(16) float act[2][4][HID];    // double-buffered gates

    // Stage this batch element's x row: 1024 floats, one float4 per thread.
    ((float4*)xs)[tid] = ((const float4*)(x + (size_t)b * TLEN))[tid];

    // This wave's gate row (64 weights) into registers.
    const int row = w * HID + l;
    const float4* Wr = (const float4*)(W_hh + (size_t)row * HID);
    float4 wq[16];
    #pragma unroll
    for (int q = 0; q < 16; ++q) wq[q] = Wr[q];

    const float u    = W_ih[row];                 // IN == 1
    const float bias = b_ih[row] + b_hh[row];
    const float wlin = W_lin[l];

    float c = 0.0f, h = 0.0f;
    hs4[w][l] = 0.0f;
    __syncthreads();   // xs + hs4 ready

    for (int t = 0; t < TLEN; ++t) {
        const int p = t & 1;
        const float xt = xs[t];                   // same-address broadcast

        // acc = W_hh[row,:] . h  + x_t*u + bias   (h from private LDS copy)
        float acc = __builtin_fmaf(xt, u, bias);
        #pragma unroll
        for (int q = 0; q < 16; ++q) {
            const float4 hk = *(const float4*)&hs4[w][4 * q];  // broadcast
            acc = __builtin_fmaf(hk.x, wq[q].x, acc);
            acc = __builtin_fmaf(hk.y, wq[q].y, acc);
            acc = __builtin_fmaf(hk.z, wq[q].z, acc);
            acc = __builtin_fmaf(hk.w, wq[q].w, acc);
        }

        // This wave's activation (wave-uniform branch).
        const float a = (w == 2) ? fast_tanh(acc) : fast_sigmoid(acc);
        act[p][w][l] = a;                         // stride-1, conflict-free
        __syncthreads();                          // the ONE barrier per step

        // Redundant elementwise update in every wave.
        const float ai = act[p][0][l];
        const float af = act[p][1][l];
        const float ag = act[p][2][l];
        const float ao = act[p][3][l];
        c = __builtin_fmaf(af, c, ai * ag);
        h = ao * fast_tanh(c);
        hs4[w][l] = h;                            // private copy; no barrier
    }

    // out[b] = dot(h, W_lin) + b_lin  (wave 0 only)
    if (w == 0) {
        float v = h * wlin;
        #pragma unroll
        for (int off = 32; off > 0; off >>= 1)
            v += __shfl_down(v, off, 64);
        if (l == 0) out[b] = v + b_lin[0];
    }
}

extern "C" void kernel_launch(void* const* d_in, const int* in_sizes, int n_in,
                              void* d_out, int out_size, void* d_ws, size_t ws_size,
                              hipStream_t stream) {
    const float* x     = (const float*)d_in[0];
    const float* W_ih  = (const float*)d_in[1];
    const float* W_hh  = (const float*)d_in[2];
    const float* b_ih  = (const float*)d_in[3];
    const float* b_hh  = (const float*)d_in[4];
    const float* W_lin = (const float*)d_in[5];
    const float* b_lin = (const float*)d_in[6];
    float* out = (float*)d_out;

    const int B = out_size;  // 512
    qlstm_kernel<<<B, 256, 0, stream>>>(x, W_ih, W_hh, b_ih, b_hh, W_lin, b_lin, out);
}